// Round 1
// baseline (742.758 us; speedup 1.0000x reference)
//
#include <hip/hip_runtime.h>
#include <stdint.h>

#define NN   50000
#define NE   800000
#define FD   128
#define NLAY 4
#define NLIN 256
#define NOUTF 10
#define NGR  64
#define NB   196   // ceil(NN/256)

// ---------------- index dtype probe + normalization ----------------
// Harness may hand us int32 or int64 indices. If int64 (values < 2^31),
// every odd 32-bit word of edge_index is 0. Random src values make a
// false positive (~(1/50000)^256) impossible.
__global__ void detect_k(const unsigned* __restrict__ p, int* __restrict__ flag){
    __shared__ int any;
    if (threadIdx.x == 0) any = 0;
    __syncthreads();
    if (p[2*threadIdx.x + 1] != 0u) atomicOr(&any, 1);
    __syncthreads();
    if (threadIdx.x == 0) *flag = (any == 0) ? 1 : 0;   // 1 => int64
}

__global__ void conv_edges_k(const void* __restrict__ p, const int* __restrict__ flag,
                             int* __restrict__ s32, int* __restrict__ d32){
    int e = blockIdx.x*256 + threadIdx.x;
    if (e >= NE) return;
    if (*flag){
        const long long* q = (const long long*)p;
        s32[e] = (int)q[e];  d32[e] = (int)q[NE + e];
    } else {
        const int* q = (const int*)p;
        s32[e] = q[e];       d32[e] = q[NE + e];
    }
}

__global__ void conv_batch_k(const void* __restrict__ p, const int* __restrict__ flag,
                             int* __restrict__ b32){
    int i = blockIdx.x*256 + threadIdx.x;
    if (i >= NN) return;
    b32[i] = (*flag) ? (int)((const long long*)p)[i] : ((const int*)p)[i];
}

// ---------------- CSR build ----------------
__global__ void zero_k(int* __restrict__ p, int n){
    int i = blockIdx.x*256 + threadIdx.x;
    if (i < n) p[i] = 0;
}

__global__ void count_k(const int* __restrict__ d32, int* __restrict__ cnt){
    int e = blockIdx.x*256 + threadIdx.x;
    if (e < NE) atomicAdd(&cnt[d32[e]], 1);
}

__global__ void scan1_k(const int* __restrict__ cnt, int* __restrict__ rp, int* __restrict__ bsum){
    __shared__ int s[256];
    int tid = threadIdx.x;
    int i = blockIdx.x*256 + tid;
    int v = (i < NN) ? cnt[i] : 0;
    s[tid] = v;
    __syncthreads();
    for (int off = 1; off < 256; off <<= 1){
        int t = (tid >= off) ? s[tid - off] : 0;
        __syncthreads();
        if (tid >= off) s[tid] += t;
        __syncthreads();
    }
    if (i < NN) rp[i] = s[tid] - v;          // block-local exclusive
    if (tid == 255) bsum[blockIdx.x] = s[255];
}

__global__ void scan2_k(const int* __restrict__ bsum, int* __restrict__ boff){
    __shared__ int s[256];
    int tid = threadIdx.x;
    int v = (tid < NB) ? bsum[tid] : 0;
    s[tid] = v;
    __syncthreads();
    for (int off = 1; off < 256; off <<= 1){
        int t = (tid >= off) ? s[tid - off] : 0;
        __syncthreads();
        if (tid >= off) s[tid] += t;
        __syncthreads();
    }
    if (tid < NB) boff[tid] = s[tid] - v;    // exclusive block offsets
}

__global__ void scan3_k(int* __restrict__ rp, const int* __restrict__ boff,
                        const int* __restrict__ cnt, float* __restrict__ dinv){
    int i = blockIdx.x*256 + threadIdx.x;
    if (i < NN){
        rp[i] += boff[blockIdx.x];
        dinv[i] = rsqrtf((float)(cnt[i] + 1));   // +1 self-loop
    }
    if (i == NN-1) rp[NN] = NE;
}

__global__ void scatter_k(const int* __restrict__ s32, const int* __restrict__ d32,
                          const int* __restrict__ rp, int* __restrict__ cursor,
                          const float* __restrict__ dinv, int2* __restrict__ cn){
    int e = blockIdx.x*256 + threadIdx.x;
    if (e >= NE) return;
    int s = s32[e], d = d32[e];
    int slot = rp[d] + atomicAdd(&cursor[d], 1);
    cn[slot] = make_int2(s, __float_as_int(dinv[s] * dinv[d]));
}

// ---------------- graph segment boundaries (batch is sorted) ----------------
__global__ void bound_k(const int* __restrict__ b32, int* __restrict__ gstart){
    int i = blockIdx.x*256 + threadIdx.x;
    if (i >= NN) return;
    int b = b32[i];
    if (i == 0){
        for (int g = 0; g <= b; ++g) gstart[g] = 0;
    } else {
        int p = b32[i-1];
        for (int g = p+1; g <= b; ++g) gstart[g] = i;
    }
    if (i == NN-1){
        for (int g = b+1; g <= NGR; ++g) gstart[g] = NN;
    }
}

// ---------------- f32 GEMM: T[M,128] = A[M,128] @ W[128,128] ----------------
// 128x128 tile, 256 threads, 8x8 micro-tile. A staged transposed in LDS.
__global__ __launch_bounds__(256) void gemm_k(const float* __restrict__ A,
                                              const float* __restrict__ W,
                                              float* __restrict__ T){
    __shared__ float As[FD][132];   // As[k][r] = A[row0+r][k]
    __shared__ float Wl[FD][132];   // Wl[k][c]
    const int tid = threadIdx.x;
    const int row0 = blockIdx.x * 128;

    // stage W (128x128 = 4096 float4 / 256 thr = 16 each), coalesced
    #pragma unroll
    for (int j = 0; j < 16; ++j){
        int q = tid + 256*j;
        int k = q >> 5;
        int c = (q & 31) * 4;
        float4 w = *reinterpret_cast<const float4*>(W + k*FD + c);
        *reinterpret_cast<float4*>(&Wl[k][c]) = w;
    }
    // stage A transposed
    {
        int r  = tid >> 1;
        int kb = (tid & 1) * 64;
        int gr = row0 + r;
        bool ok = gr < NN;
        const float* Ar = A + (long)gr * FD;
        #pragma unroll
        for (int j = 0; j < 16; ++j){
            int k = kb + j*4;
            float4 a = ok ? *reinterpret_cast<const float4*>(Ar + k)
                          : make_float4(0.f,0.f,0.f,0.f);
            As[k+0][r] = a.x; As[k+1][r] = a.y; As[k+2][r] = a.z; As[k+3][r] = a.w;
        }
    }
    __syncthreads();

    const int tx = tid & 15, ty = tid >> 4;
    const int ra = ty * 8;           // 8 rows
    const int ca = tx * 4;           // cols ca..ca+3 and ca+64..ca+67
    float acc[8][8];
    #pragma unroll
    for (int i = 0; i < 8; ++i)
        #pragma unroll
        for (int j = 0; j < 8; ++j) acc[i][j] = 0.f;

    #pragma unroll 4
    for (int k = 0; k < FD; ++k){
        float4 a0 = *reinterpret_cast<const float4*>(&As[k][ra]);
        float4 a1 = *reinterpret_cast<const float4*>(&As[k][ra+4]);
        float4 w0 = *reinterpret_cast<const float4*>(&Wl[k][ca]);
        float4 w1 = *reinterpret_cast<const float4*>(&Wl[k][ca+64]);
        float av[8] = {a0.x,a0.y,a0.z,a0.w,a1.x,a1.y,a1.z,a1.w};
        float wv[8] = {w0.x,w0.y,w0.z,w0.w,w1.x,w1.y,w1.z,w1.w};
        #pragma unroll
        for (int i = 0; i < 8; ++i)
            #pragma unroll
            for (int j = 0; j < 8; ++j)
                acc[i][j] = fmaf(av[i], wv[j], acc[i][j]);
    }

    #pragma unroll
    for (int i = 0; i < 8; ++i){
        int gr = row0 + ra + i;
        if (gr < NN){
            float4 o0 = make_float4(acc[i][0],acc[i][1],acc[i][2],acc[i][3]);
            float4 o1 = make_float4(acc[i][4],acc[i][5],acc[i][6],acc[i][7]);
            *reinterpret_cast<float4*>(T + (long)gr*FD + ca)      = o0;
            *reinterpret_cast<float4*>(T + (long)gr*FD + ca + 64) = o1;
        }
    }
}

// ---------------- aggregation: h[v] = relu(sum_e norm*t[src] + t[v]/deg + b) ----------------
__global__ __launch_bounds__(128) void agg_k(const float* __restrict__ t,
                                             const int* __restrict__ rp,
                                             const int2* __restrict__ cn,
                                             const float* __restrict__ dinv,
                                             const float* __restrict__ bias,
                                             float* __restrict__ h){
    int v = blockIdx.x;
    int f = threadIdx.x;
    float di = dinv[v];
    float val = t[(long)v*FD + f] * (di*di);      // self-loop: norm = 1/deg
    int e0 = rp[v], e1 = rp[v+1];
    for (int e = e0; e < e1; ++e){
        int2 p = cn[e];
        val = fmaf(__int_as_float(p.y), t[(long)p.x*FD + f], val);
    }
    val += bias[f];
    h[(long)v*FD + f] = fmaxf(val, 0.f);
}

// ---------------- per-layer global max pool (h >= 0, so uint-bit atomicMax is exact) ----------------
__global__ __launch_bounds__(128) void pool_k(const float* __restrict__ h,
                                              const int* __restrict__ gstart,
                                              unsigned* __restrict__ gbuf, int l){
    int g = blockIdx.x, part = blockIdx.y, f = threadIdx.x;
    int s0 = gstart[g], s1 = gstart[g+1];
    int len = s1 - s0;
    int chunk = (len + 7) >> 3;
    int a = s0 + part*chunk;
    int b = min(a + chunk, s1);
    float m = 0.f;
    for (int i = a; i < b; ++i) m = fmaxf(m, h[(long)i*FD + f]);
    atomicMax(&gbuf[g*(NLAY*FD) + l*FD + f], __float_as_uint(m));
}

// ---------------- head: out = relu(g @ Wlin + blin) @ Wout + bout ----------------
__global__ __launch_bounds__(256) void head_k(const unsigned* __restrict__ gbuf,
                                              const float* __restrict__ Wlin,
                                              const float* __restrict__ blin,
                                              const float* __restrict__ Wout,
                                              const float* __restrict__ bout,
                                              float* __restrict__ out){
    __shared__ float gs[NLAY*FD];
    __shared__ float us[NLIN];
    int g = blockIdx.x, tid = threadIdx.x;
    gs[tid]       = __uint_as_float(gbuf[g*(NLAY*FD) + tid]);
    gs[tid + 256] = __uint_as_float(gbuf[g*(NLAY*FD) + 256 + tid]);
    __syncthreads();
    float acc = blin[tid];
    #pragma unroll 8
    for (int k = 0; k < NLAY*FD; ++k) acc = fmaf(gs[k], Wlin[k*NLIN + tid], acc);
    us[tid] = fmaxf(acc, 0.f);
    __syncthreads();
    if (tid < NOUTF){
        float o = bout[tid];
        for (int k = 0; k < NLIN; ++k) o = fmaf(us[k], Wout[k*NOUTF + tid], o);
        out[g*NOUTF + tid] = o;
    }
}

// ---------------- launch ----------------
extern "C" void kernel_launch(void* const* d_in, const int* in_sizes, int n_in,
                              void* d_out, int out_size, void* d_ws, size_t ws_size,
                              hipStream_t stream){
    const float* x    = (const float*)d_in[0];
    const void*  eidx = d_in[1];
    const void*  batv = d_in[2];
    const float* Wsp  = (const float*)d_in[4];
    const float* bsp  = (const float*)d_in[5];
    const float* Wlin = (const float*)d_in[6];
    const float* blin = (const float*)d_in[7];
    const float* Wout = (const float*)d_in[8];
    const float* bout = (const float*)d_in[9];
    float* out = (float*)d_out;

    uintptr_t cur = (uintptr_t)d_ws;
    auto alloc = [&](size_t bytes)->void*{
        cur = (cur + 255) & ~(uintptr_t)255;
        void* p = (void*)cur;
        cur += bytes;
        return p;
    };
    float* t     = (float*)alloc((size_t)NN*FD*4);
    float* h     = (float*)alloc((size_t)NN*FD*4);
    int*   s32   = (int*)  alloc((size_t)NE*4);
    int*   d32   = (int*)  alloc((size_t)NE*4);
    int2*  cn    = (int2*) alloc((size_t)NE*8);
    int*   rp    = (int*)  alloc((size_t)(NN+1)*4);
    float* dinv  = (float*)alloc((size_t)NN*4);
    int*   bsum  = (int*)  alloc(256*4);
    int*   boff  = (int*)  alloc(256*4);
    int*   gst   = (int*)  alloc((NGR+1)*4);
    int*   b32   = (int*)  alloc((size_t)NN*4);
    int*   flag  = (int*)  alloc(4);
    // contiguous zero region: cnt | cursor | gbuf
    int*      cnt    = (int*)     alloc((size_t)NN*4);
    int*      cursor = (int*)     alloc((size_t)NN*4);
    unsigned* gbuf   = (unsigned*)alloc((size_t)NGR*NLAY*FD*4);
    int zero_n = (int)((cur - (uintptr_t)cnt + 3) / 4);

    detect_k    <<<1, 256, 0, stream>>>((const unsigned*)eidx, flag);
    conv_edges_k<<<(NE+255)/256, 256, 0, stream>>>(eidx, flag, s32, d32);
    conv_batch_k<<<(NN+255)/256, 256, 0, stream>>>(batv, flag, b32);
    zero_k      <<<(zero_n+255)/256, 256, 0, stream>>>(cnt, zero_n);
    count_k     <<<(NE+255)/256, 256, 0, stream>>>(d32, cnt);
    scan1_k     <<<NB, 256, 0, stream>>>(cnt, rp, bsum);
    scan2_k     <<<1, 256, 0, stream>>>(bsum, boff);
    scan3_k     <<<NB, 256, 0, stream>>>(rp, boff, cnt, dinv);
    scatter_k   <<<(NE+255)/256, 256, 0, stream>>>(s32, d32, rp, cursor, dinv, cn);
    bound_k     <<<(NN+255)/256, 256, 0, stream>>>(b32, gst);

    for (int l = 0; l < NLAY; ++l){
        const float* hin = (l == 0) ? x : (const float*)h;
        gemm_k<<<(NN+127)/128, 256, 0, stream>>>(hin, Wsp + (size_t)l*FD*FD, t);
        agg_k <<<NN, 128, 0, stream>>>(t, rp, cn, dinv, bsp + (size_t)l*FD, h);
        pool_k<<<dim3(NGR, 8), 128, 0, stream>>>(h, gst, gbuf, l);
    }
    head_k<<<NGR, 256, 0, stream>>>(gbuf, Wlin, blin, Wout, bout, out);
}

// Round 2
// 471.541 us; speedup vs baseline: 1.5752x; 1.5752x over previous
//
#include <hip/hip_runtime.h>
#include <stdint.h>

#define NN   50000
#define NE   800000
#define FD   128
#define NLAY 4
#define NLIN 256
#define NOUTF 10
#define NGR  64
#define NB   196   // ceil(NN/256)

typedef _Float16 half8  __attribute__((ext_vector_type(8)));
typedef _Float16 half4  __attribute__((ext_vector_type(4)));
typedef _Float16 half2t __attribute__((ext_vector_type(2)));
typedef float    f32x4  __attribute__((ext_vector_type(4)));

// ---------------- index dtype probe + normalization ----------------
__global__ void detect_k(const unsigned* __restrict__ p, int* __restrict__ flag){
    __shared__ int any;
    if (threadIdx.x == 0) any = 0;
    __syncthreads();
    if (p[2*threadIdx.x + 1] != 0u) atomicOr(&any, 1);
    __syncthreads();
    if (threadIdx.x == 0) *flag = (any == 0) ? 1 : 0;   // 1 => int64
}

__global__ void conv_edges_k(const void* __restrict__ p, const int* __restrict__ flag,
                             int* __restrict__ s32, int* __restrict__ d32){
    int e = blockIdx.x*256 + threadIdx.x;
    if (e >= NE) return;
    if (*flag){
        const long long* q = (const long long*)p;
        s32[e] = (int)q[e];  d32[e] = (int)q[NE + e];
    } else {
        const int* q = (const int*)p;
        s32[e] = q[e];       d32[e] = q[NE + e];
    }
}

__global__ void conv_batch_k(const void* __restrict__ p, const int* __restrict__ flag,
                             int* __restrict__ b32){
    int i = blockIdx.x*256 + threadIdx.x;
    if (i >= NN) return;
    b32[i] = (*flag) ? (int)((const long long*)p)[i] : ((const int*)p)[i];
}

// ---------------- fp16 prep ----------------
__global__ void prep_w_k(const float* __restrict__ Ws, _Float16* __restrict__ WT){
    // WT[l][c][k] = Ws[l][k][c]
    int idx = blockIdx.x*256 + threadIdx.x;
    if (idx >= NLAY*FD*FD) return;
    int l = idx >> 14;
    int r = idx & 16383;
    int c = r >> 7, k = r & 127;
    WT[idx] = (_Float16)Ws[(l<<14) + (k<<7) + c];
}

__global__ void prep_x_k(const float* __restrict__ x, _Float16* __restrict__ xh){
    int i = blockIdx.x*256 + threadIdx.x;
    if (i >= NN*FD/4) return;
    float4 v = reinterpret_cast<const float4*>(x)[i];
    half4 o; o[0] = (_Float16)v.x; o[1] = (_Float16)v.y; o[2] = (_Float16)v.z; o[3] = (_Float16)v.w;
    reinterpret_cast<half4*>(xh)[i] = o;
}

// ---------------- CSR build ----------------
__global__ void zero_k(int* __restrict__ p, int n){
    int i = blockIdx.x*256 + threadIdx.x;
    if (i < n) p[i] = 0;
}

__global__ void count_k(const int* __restrict__ d32, int* __restrict__ cnt){
    int e = blockIdx.x*256 + threadIdx.x;
    if (e < NE) atomicAdd(&cnt[d32[e]], 1);
}

__global__ void scan1_k(const int* __restrict__ cnt, int* __restrict__ rp, int* __restrict__ bsum){
    __shared__ int s[256];
    int tid = threadIdx.x;
    int i = blockIdx.x*256 + tid;
    int v = (i < NN) ? cnt[i] : 0;
    s[tid] = v;
    __syncthreads();
    for (int off = 1; off < 256; off <<= 1){
        int t = (tid >= off) ? s[tid - off] : 0;
        __syncthreads();
        if (tid >= off) s[tid] += t;
        __syncthreads();
    }
    if (i < NN) rp[i] = s[tid] - v;
    if (tid == 255) bsum[blockIdx.x] = s[255];
}

__global__ void scan2_k(const int* __restrict__ bsum, int* __restrict__ boff){
    __shared__ int s[256];
    int tid = threadIdx.x;
    int v = (tid < NB) ? bsum[tid] : 0;
    s[tid] = v;
    __syncthreads();
    for (int off = 1; off < 256; off <<= 1){
        int t = (tid >= off) ? s[tid - off] : 0;
        __syncthreads();
        if (tid >= off) s[tid] += t;
        __syncthreads();
    }
    if (tid < NB) boff[tid] = s[tid] - v;
}

__global__ void scan3_k(int* __restrict__ rp, const int* __restrict__ boff,
                        const int* __restrict__ cnt, float* __restrict__ dinv){
    int i = blockIdx.x*256 + threadIdx.x;
    if (i < NN){
        rp[i] += boff[blockIdx.x];
        dinv[i] = rsqrtf((float)(cnt[i] + 1));
    }
    if (i == NN-1) rp[NN] = NE;
}

__global__ void scatter_k(const int* __restrict__ s32, const int* __restrict__ d32,
                          const int* __restrict__ rp, int* __restrict__ cursor,
                          const float* __restrict__ dinv, int2* __restrict__ cn){
    int e = blockIdx.x*256 + threadIdx.x;
    if (e >= NE) return;
    int s = s32[e], d = d32[e];
    int slot = rp[d] + atomicAdd(&cursor[d], 1);
    cn[slot] = make_int2(s, __float_as_int(dinv[s] * dinv[d]));
}

// ---------------- graph segment boundaries (batch sorted) ----------------
__global__ void bound_k(const int* __restrict__ b32, int* __restrict__ gstart){
    int i = blockIdx.x*256 + threadIdx.x;
    if (i >= NN) return;
    int b = b32[i];
    if (i == 0){
        for (int g = 0; g <= b; ++g) gstart[g] = 0;
    } else {
        int p = b32[i-1];
        for (int g = p+1; g <= b; ++g) gstart[g] = i;
    }
    if (i == NN-1){
        for (int g = b+1; g <= NGR; ++g) gstart[g] = NN;
    }
}

// ---------------- fp16 MFMA GEMM: T[M,128] = A[M,128] @ W, W given as WT[c][k] ----------------
// Block = 256 thr = 4 waves (2x2), block tile 128 rows x 128 cols, all frags in registers.
// Operands swapped: D-tile = t^T, so each lane holds 4 CONSECUTIVE feature cols of one node row.
__global__ __launch_bounds__(256) void gemm_k(const _Float16* __restrict__ A,
                                              const _Float16* __restrict__ WT,
                                              _Float16* __restrict__ T){
    const int tid  = threadIdx.x;
    const int lane = tid & 63;
    const int wid  = tid >> 6;
    const int wr   = (wid >> 1) * 64;   // wave row offset in tile
    const int wc   = (wid & 1) * 64;    // wave col offset
    const long r0  = (long)blockIdx.x * 128 + wr;
    const int lr   = lane & 15;
    const int lk   = (lane >> 4) * 8;

    // A-operand fragments: columns of W (rows of WT), contiguous 16B
    half8 wf[4][4];
    #pragma unroll
    for (int n = 0; n < 4; ++n)
        #pragma unroll
        for (int kk = 0; kk < 4; ++kk)
            wf[n][kk] = *reinterpret_cast<const half8*>(WT + (wc + n*16 + lr)*FD + kk*32 + lk);

    f32x4 acc[4][4];
    #pragma unroll
    for (int m = 0; m < 4; ++m)
        #pragma unroll
        for (int n = 0; n < 4; ++n)
            acc[m][n] = (f32x4){0.f,0.f,0.f,0.f};

    #pragma unroll
    for (int kk = 0; kk < 4; ++kk){
        half8 af[4];
        #pragma unroll
        for (int m = 0; m < 4; ++m){
            long row = r0 + m*16 + lr;
            if (row < NN)
                af[m] = *reinterpret_cast<const half8*>(A + row*FD + kk*32 + lk);
            else
                af[m] = (half8)(_Float16)0;
        }
        #pragma unroll
        for (int m = 0; m < 4; ++m)
            #pragma unroll
            for (int n = 0; n < 4; ++n)
                acc[m][n] = __builtin_amdgcn_mfma_f32_16x16x32_f16(wf[n][kk], af[m], acc[m][n], 0, 0, 0);
    }

    // lane holds t[r0+m*16+(lane&15)][wc+n*16+(lane>>4)*4 + q], q=0..3 -> one 8B store
    #pragma unroll
    for (int m = 0; m < 4; ++m){
        long row = r0 + m*16 + lr;
        if (row >= NN) continue;
        #pragma unroll
        for (int n = 0; n < 4; ++n){
            half4 o;
            o[0] = (_Float16)acc[m][n][0];
            o[1] = (_Float16)acc[m][n][1];
            o[2] = (_Float16)acc[m][n][2];
            o[3] = (_Float16)acc[m][n][3];
            *reinterpret_cast<half4*>(T + row*FD + wc + n*16 + (lane>>4)*4) = o;
        }
    }
}

// ---------------- aggregation: one wave per node, fp16 gather, f32 accumulate ----------------
__global__ __launch_bounds__(256) void agg_k(const _Float16* __restrict__ t,
                                             const int* __restrict__ rp,
                                             const int2* __restrict__ cn,
                                             const float* __restrict__ dinv,
                                             const float* __restrict__ bias,
                                             _Float16* __restrict__ h){
    int v = blockIdx.x*4 + (threadIdx.x >> 6);
    if (v >= NN) return;
    int lane = threadIdx.x & 63;
    const half2t* t2 = reinterpret_cast<const half2t*>(t);

    float di = dinv[v];
    half2t sv = t2[(long)v*64 + lane];
    float a0 = (float)sv[0] * (di*di);
    float a1 = (float)sv[1] * (di*di);

    int e0 = rp[v], e1 = rp[v+1];
    int e = e0;
    for (; e + 4 <= e1; e += 4){
        int2 p0 = cn[e+0], p1 = cn[e+1], p2 = cn[e+2], p3 = cn[e+3];
        half2t g0 = t2[(long)p0.x*64 + lane];
        half2t g1 = t2[(long)p1.x*64 + lane];
        half2t g2 = t2[(long)p2.x*64 + lane];
        half2t g3 = t2[(long)p3.x*64 + lane];
        float n0 = __int_as_float(p0.y), n1 = __int_as_float(p1.y);
        float n2 = __int_as_float(p2.y), n3 = __int_as_float(p3.y);
        a0 = fmaf(n0, (float)g0[0], a0); a1 = fmaf(n0, (float)g0[1], a1);
        a0 = fmaf(n1, (float)g1[0], a0); a1 = fmaf(n1, (float)g1[1], a1);
        a0 = fmaf(n2, (float)g2[0], a0); a1 = fmaf(n2, (float)g2[1], a1);
        a0 = fmaf(n3, (float)g3[0], a0); a1 = fmaf(n3, (float)g3[1], a1);
    }
    for (; e < e1; ++e){
        int2 p = cn[e];
        half2t g = t2[(long)p.x*64 + lane];
        float nw = __int_as_float(p.y);
        a0 = fmaf(nw, (float)g[0], a0);
        a1 = fmaf(nw, (float)g[1], a1);
    }
    float2 b = *reinterpret_cast<const float2*>(bias + 2*lane);
    a0 = fmaxf(a0 + b.x, 0.f);
    a1 = fmaxf(a1 + b.y, 0.f);
    half2t o; o[0] = (_Float16)a0; o[1] = (_Float16)a1;
    reinterpret_cast<half2t*>(h)[(long)v*64 + lane] = o;
}

// ---------------- per-layer global max pool ----------------
__global__ __launch_bounds__(64) void pool_k(const _Float16* __restrict__ h,
                                             const int* __restrict__ gstart,
                                             unsigned* __restrict__ gbuf, int l){
    int g = blockIdx.x, part = blockIdx.y, lane = threadIdx.x;
    int s0 = gstart[g], s1 = gstart[g+1];
    int len = s1 - s0;
    int chunk = (len + 7) >> 3;
    int a = s0 + part*chunk;
    int b = min(a + chunk, s1);
    const half2t* h2 = reinterpret_cast<const half2t*>(h);
    float m0 = 0.f, m1 = 0.f;
    for (int i = a; i < b; ++i){
        half2t x = h2[(long)i*64 + lane];
        m0 = fmaxf(m0, (float)x[0]);
        m1 = fmaxf(m1, (float)x[1]);
    }
    atomicMax(&gbuf[g*(NLAY*FD) + l*FD + 2*lane    ], __float_as_uint(m0));
    atomicMax(&gbuf[g*(NLAY*FD) + l*FD + 2*lane + 1], __float_as_uint(m1));
}

// ---------------- head ----------------
__global__ __launch_bounds__(256) void head_k(const unsigned* __restrict__ gbuf,
                                              const float* __restrict__ Wlin,
                                              const float* __restrict__ blin,
                                              const float* __restrict__ Wout,
                                              const float* __restrict__ bout,
                                              float* __restrict__ out){
    __shared__ float gs[NLAY*FD];
    __shared__ float us[NLIN];
    int g = blockIdx.x, tid = threadIdx.x;
    gs[tid]       = __uint_as_float(gbuf[g*(NLAY*FD) + tid]);
    gs[tid + 256] = __uint_as_float(gbuf[g*(NLAY*FD) + 256 + tid]);
    __syncthreads();
    float acc = blin[tid];
    #pragma unroll 8
    for (int k = 0; k < NLAY*FD; ++k) acc = fmaf(gs[k], Wlin[k*NLIN + tid], acc);
    us[tid] = fmaxf(acc, 0.f);
    __syncthreads();
    if (tid < NOUTF){
        float o = bout[tid];
        for (int k = 0; k < NLIN; ++k) o = fmaf(us[k], Wout[k*NOUTF + tid], o);
        out[g*NOUTF + tid] = o;
    }
}

// ---------------- launch ----------------
extern "C" void kernel_launch(void* const* d_in, const int* in_sizes, int n_in,
                              void* d_out, int out_size, void* d_ws, size_t ws_size,
                              hipStream_t stream){
    const float* x    = (const float*)d_in[0];
    const void*  eidx = d_in[1];
    const void*  batv = d_in[2];
    const float* Wsp  = (const float*)d_in[4];
    const float* bsp  = (const float*)d_in[5];
    const float* Wlin = (const float*)d_in[6];
    const float* blin = (const float*)d_in[7];
    const float* Wout = (const float*)d_in[8];
    const float* bout = (const float*)d_in[9];
    float* out = (float*)d_out;

    uintptr_t cur = (uintptr_t)d_ws;
    auto alloc = [&](size_t bytes)->void*{
        cur = (cur + 255) & ~(uintptr_t)255;
        void* p = (void*)cur;
        cur += bytes;
        return p;
    };
    _Float16* xh   = (_Float16*)alloc((size_t)NN*FD*2);
    _Float16* t    = (_Float16*)alloc((size_t)NN*FD*2);
    _Float16* h    = (_Float16*)alloc((size_t)NN*FD*2);
    _Float16* WT   = (_Float16*)alloc((size_t)NLAY*FD*FD*2);
    int*   s32   = (int*)  alloc((size_t)NE*4);
    int*   d32   = (int*)  alloc((size_t)NE*4);
    int2*  cn    = (int2*) alloc((size_t)NE*8);
    int*   rp    = (int*)  alloc((size_t)(NN+1)*4);
    float* dinv  = (float*)alloc((size_t)NN*4);
    int*   bsum  = (int*)  alloc(256*4);
    int*   boff  = (int*)  alloc(256*4);
    int*   gst   = (int*)  alloc((NGR+1)*4);
    int*   b32   = (int*)  alloc((size_t)NN*4);
    int*   flag  = (int*)  alloc(4);
    // contiguous zero region: cnt | cursor | gbuf
    int*      cnt    = (int*)     alloc((size_t)NN*4);
    int*      cursor = (int*)     alloc((size_t)NN*4);
    unsigned* gbuf   = (unsigned*)alloc((size_t)NGR*NLAY*FD*4);
    int zero_n = (int)((cur - (uintptr_t)cnt + 3) / 4);

    detect_k    <<<1, 256, 0, stream>>>((const unsigned*)eidx, flag);
    conv_edges_k<<<(NE+255)/256, 256, 0, stream>>>(eidx, flag, s32, d32);
    conv_batch_k<<<(NN+255)/256, 256, 0, stream>>>(batv, flag, b32);
    prep_w_k    <<<(NLAY*FD*FD+255)/256, 256, 0, stream>>>(Wsp, WT);
    prep_x_k    <<<(NN*FD/4+255)/256, 256, 0, stream>>>(x, xh);
    zero_k      <<<(zero_n+255)/256, 256, 0, stream>>>(cnt, zero_n);
    count_k     <<<(NE+255)/256, 256, 0, stream>>>(d32, cnt);
    scan1_k     <<<NB, 256, 0, stream>>>(cnt, rp, bsum);
    scan2_k     <<<1, 256, 0, stream>>>(bsum, boff);
    scan3_k     <<<NB, 256, 0, stream>>>(rp, boff, cnt, dinv);
    scatter_k   <<<(NE+255)/256, 256, 0, stream>>>(s32, d32, rp, cursor, dinv, cn);
    bound_k     <<<(NN+255)/256, 256, 0, stream>>>(b32, gst);

    for (int l = 0; l < NLAY; ++l){
        const _Float16* hin = (l == 0) ? xh : (const _Float16*)h;
        gemm_k<<<(NN+127)/128, 256, 0, stream>>>(hin, WT + (size_t)l*FD*FD, t);
        agg_k <<<(NN+3)/4, 256, 0, stream>>>(t, rp, cn, dinv, bsp + (size_t)l*FD, h);
        pool_k<<<dim3(NGR, 8), 64, 0, stream>>>(h, gst, gbuf, l);
    }
    head_k<<<NGR, 256, 0, stream>>>(gbuf, Wlin, blin, Wout, bout, out);
}